// Round 1
// baseline (1098.501 us; speedup 1.0000x reference)
//
#include <hip/hip_runtime.h>
#include <hip/hip_bf16.h>

// QuantizedLinear: out[m,o] = sum_k x[m,k] * (q[o,k]-z[o,g(k)])*s[o,g(k)] + b[o]
// M=8192 (4*2048), K=4096, N=11008, GROUP=128.
// Plan: pass1 dequant W -> bf16 (ws), convert x -> bf16 (ws); pass2 bf16 MFMA GEMM
// (128x128 tile, BK=64, global_load_lds w=16, T2 LDS swizzle, T1 XCD swizzle).

#define K_DIM 4096
#define N_DIM 11008
#define M_DIM 8192
#define NGRP 32

typedef __bf16 bf16x8 __attribute__((ext_vector_type(8)));
typedef float f32x4 __attribute__((ext_vector_type(4)));
typedef unsigned short u16x8 __attribute__((ext_vector_type(8)));

__device__ __forceinline__ unsigned short f2bf(float f) {
  unsigned u = __builtin_bit_cast(unsigned, f);
  return (unsigned short)((u + 0x7FFFu + ((u >> 16) & 1u)) >> 16);  // RNE
}

__device__ __forceinline__ void gload_lds16(const void* g, void* l) {
  __builtin_amdgcn_global_load_lds(
      (const __attribute__((address_space(1))) unsigned int*)(unsigned long long)g,
      (__attribute__((address_space(3))) unsigned int*)(unsigned int)(unsigned long long)l,
      16, 0, 0);
}

// ---- pass 1a: x fp32 -> bf16, 8 elems/thread ----
__global__ __launch_bounds__(256) void cvt_x_kernel(const float4* __restrict__ x4,
                                                    u16x8* __restrict__ xb) {
  int i = blockIdx.x * 256 + threadIdx.x;
  float4 a = x4[2 * i], b = x4[2 * i + 1];
  u16x8 r;
  r[0] = f2bf(a.x); r[1] = f2bf(a.y); r[2] = f2bf(a.z); r[3] = f2bf(a.w);
  r[4] = f2bf(b.x); r[5] = f2bf(b.y); r[6] = f2bf(b.z); r[7] = f2bf(b.w);
  xb[i] = r;
}

// ---- pass 1b: dequant W -> bf16, 8 elems/thread (one group -> one s,z) ----
__global__ __launch_bounds__(256) void dequant_kernel(const int4* __restrict__ q4,
                                                      const float* __restrict__ scales,
                                                      const float* __restrict__ zeros,
                                                      u16x8* __restrict__ wb) {
  int t = blockIdx.x * 256 + threadIdx.x;  // t < N_DIM*K_DIM/8
  int o = t >> 9;                          // row (out feature); 512 chunks per row
  int j8 = t & 511;                        // 8-elem chunk within row
  int g = j8 >> 4;                         // group = (j8*8)/128
  float s = scales[o * NGRP + g];
  float z = zeros[o * NGRP + g];
  float nzs = -z * s;
  int4 qa = q4[2 * t], qb = q4[2 * t + 1];
  u16x8 r;
  r[0] = f2bf(fmaf((float)qa.x, s, nzs));
  r[1] = f2bf(fmaf((float)qa.y, s, nzs));
  r[2] = f2bf(fmaf((float)qa.z, s, nzs));
  r[3] = f2bf(fmaf((float)qa.w, s, nzs));
  r[4] = f2bf(fmaf((float)qb.x, s, nzs));
  r[5] = f2bf(fmaf((float)qb.y, s, nzs));
  r[6] = f2bf(fmaf((float)qb.z, s, nzs));
  r[7] = f2bf(fmaf((float)qb.w, s, nzs));
  wb[t] = r;
}

// ---- pass 2: bf16 GEMM, A[M][K] x B[N][K] (B^T layout) + bias -> C[M][N] fp32 ----
// 128x128 tile, BK=64, 4 waves (2x2), each wave 64x64 = 4x4 frags of 16x16x32.
// LDS [128][64] bf16, T2 swizzle: stored[r][sl] = global[r][sl ^ (r&7)] (16B slots),
// achieved by inverse-swizzling the per-lane GLOBAL source of global_load_lds (rule #21).
__global__ __launch_bounds__(256) void gemm_kernel(const unsigned short* __restrict__ A,
                                                   const unsigned short* __restrict__ B,
                                                   const float* __restrict__ bias,
                                                   float* __restrict__ C) {
  __shared__ unsigned short sA[128 * 64];
  __shared__ unsigned short sB[128 * 64];

  const int bid = blockIdx.x;
  // T1: XCD-aware swizzle; nwg=5504, 5504%8==0 -> simple form is bijective.
  const int swz = (bid & 7) * (5504 / 8) + (bid >> 3);
  const int tm = swz / 86;
  const int tn = swz % 86;

  const int tid = threadIdx.x;
  const int w = tid >> 6;
  const int l = tid & 63;
  const int wr = w >> 1, wc = w & 1;

  // staging: each wave call j covers 8 rows (1024B); lane l -> row l>>3, slot l&7.
  const int lrow = l >> 3;
  const int gslot = (l & 7) ^ lrow;  // inverse swizzle on global source
  const unsigned short* ga = A + (tm * 128 + w * 32 + lrow) * K_DIM + gslot * 8;
  const unsigned short* gb = B + (tn * 128 + w * 32 + lrow) * K_DIM + gslot * 8;
  unsigned short* la = &sA[w * 4 * 512];
  unsigned short* lb = &sB[w * 4 * 512];

  // fragment read coords
  const int fr = l & 15;   // row-within-16 (M for A-frag, N for B-frag)
  const int sb = l >> 4;   // k-slot base 0..3
  const int x7 = l & 7;    // row&7 for swizzled read
  const int abase = (wr * 64 + fr) * 64;
  const int bbase = (wc * 64 + fr) * 64;

  f32x4 acc[4][4] = {};

  for (int kt = 0; kt < K_DIM / 64; ++kt) {
    const unsigned short* gak = ga + kt * 64;
    const unsigned short* gbk = gb + kt * 64;
#pragma unroll
    for (int j = 0; j < 4; ++j) {
      gload_lds16(gak + j * (8 * K_DIM), la + j * 512);
      gload_lds16(gbk + j * (8 * K_DIM), lb + j * 512);
    }
    __syncthreads();  // compiler emits vmcnt(0) drain before barrier
#pragma unroll
    for (int kk = 0; kk < 2; ++kk) {
      bf16x8 av[4], bv[4];
#pragma unroll
      for (int m = 0; m < 4; ++m)
        av[m] = *(const bf16x8*)&sA[abase + m * 1024 + ((((kk * 4) + sb) ^ x7) * 8)];
#pragma unroll
      for (int n = 0; n < 4; ++n)
        bv[n] = *(const bf16x8*)&sB[bbase + n * 1024 + ((((kk * 4) + sb) ^ x7) * 8)];
#pragma unroll
      for (int m = 0; m < 4; ++m)
#pragma unroll
        for (int n = 0; n < 4; ++n)
          acc[m][n] = __builtin_amdgcn_mfma_f32_16x16x32_bf16(av[m], bv[n], acc[m][n], 0, 0, 0);
    }
    __syncthreads();
  }

  // epilogue: C/D layout col=lane&15, row=(lane>>4)*4+reg (m89-verified)
  const int col0 = tn * 128 + wc * 64 + fr;
  const int row0 = tm * 128 + wr * 64 + sb * 4;
#pragma unroll
  for (int n = 0; n < 4; ++n) {
    const float bval = bias[col0 + n * 16];
#pragma unroll
    for (int m = 0; m < 4; ++m) {
#pragma unroll
      for (int jj = 0; jj < 4; ++jj) {
        C[(row0 + m * 16 + jj) * N_DIM + (col0 + n * 16)] = acc[m][n][jj] + bval;
      }
    }
  }
}

extern "C" void kernel_launch(void* const* d_in, const int* in_sizes, int n_in,
                              void* d_out, int out_size, void* d_ws, size_t ws_size,
                              hipStream_t stream) {
  const float* x = (const float*)d_in[0];
  const int* qw = (const int*)d_in[1];
  const float* sc = (const float*)d_in[2];
  const float* zr = (const float*)d_in[3];
  const float* bs = (const float*)d_in[4];
  float* out = (float*)d_out;

  const size_t xb_bytes = (size_t)M_DIM * K_DIM * 2;  // 67,108,864
  const size_t wb_bytes = (size_t)N_DIM * K_DIM * 2;  // 90,177,536
  if (ws_size < xb_bytes + wb_bytes) return;  // signals ws-too-small via validation fail

  unsigned short* xb = (unsigned short*)d_ws;
  unsigned short* wb = (unsigned short*)((char*)d_ws + xb_bytes);

  cvt_x_kernel<<<(M_DIM * K_DIM / 8) / 256, 256, 0, stream>>>((const float4*)x, (u16x8*)xb);
  dequant_kernel<<<(N_DIM * K_DIM / 8) / 256, 256, 0, stream>>>((const int4*)qw, sc, zr,
                                                                (u16x8*)wb);
  gemm_kernel<<<(M_DIM / 128) * (N_DIM / 128), 256, 0, stream>>>(xb, wb, bs, out);
}

// Round 2
// 758.659 us; speedup vs baseline: 1.4480x; 1.4480x over previous
//
#include <hip/hip_runtime.h>
#include <hip/hip_bf16.h>

// QuantizedLinear: out[m,o] = sum_k x[m,k] * (q[o,k]-z[o,g])*s[o,g] + b[o]
// M=8192, K=4096, N=11008. Pass1: dequant W->bf16, cvt x->bf16 (d_ws).
// Pass2: 256x256 8-phase bf16 GEMM (T1 XCD swizzle, T2 LDS swizzle, T3+T4
// counted-vmcnt 8-phase pipeline, T5 setprio) per m201 template.

#define K_DIM 4096
#define N_DIM 11008
#define M_DIM 8192
#define NGRP 32

typedef __bf16 bf16x8 __attribute__((ext_vector_type(8)));
typedef float f32x4 __attribute__((ext_vector_type(4)));
typedef unsigned short u16x8 __attribute__((ext_vector_type(8)));

__device__ __forceinline__ unsigned short f2bf(float f) {
  unsigned u = __builtin_bit_cast(unsigned, f);
  return (unsigned short)((u + 0x7FFFu + ((u >> 16) & 1u)) >> 16);  // RNE
}

__device__ __forceinline__ void gload_lds16(const void* g, void* l) {
  __builtin_amdgcn_global_load_lds(
      (const __attribute__((address_space(1))) unsigned int*)(unsigned long long)g,
      (__attribute__((address_space(3))) unsigned int*)(unsigned int)(unsigned long long)l,
      16, 0, 0);
}

// ---- pass 1a: x fp32 -> bf16 ----
__global__ __launch_bounds__(256) void cvt_x_kernel(const float4* __restrict__ x4,
                                                    u16x8* __restrict__ xb) {
  int i = blockIdx.x * 256 + threadIdx.x;
  float4 a = x4[2 * i], b = x4[2 * i + 1];
  u16x8 r;
  r[0] = f2bf(a.x); r[1] = f2bf(a.y); r[2] = f2bf(a.z); r[3] = f2bf(a.w);
  r[4] = f2bf(b.x); r[5] = f2bf(b.y); r[6] = f2bf(b.z); r[7] = f2bf(b.w);
  xb[i] = r;
}

// ---- pass 1b: dequant W -> bf16 ----
__global__ __launch_bounds__(256) void dequant_kernel(const int4* __restrict__ q4,
                                                      const float* __restrict__ scales,
                                                      const float* __restrict__ zeros,
                                                      u16x8* __restrict__ wb) {
  int t = blockIdx.x * 256 + threadIdx.x;
  int o = t >> 9;
  int j8 = t & 511;
  int g = j8 >> 4;
  float s = scales[o * NGRP + g];
  float z = zeros[o * NGRP + g];
  float nzs = -z * s;
  int4 qa = q4[2 * t], qb = q4[2 * t + 1];
  u16x8 r;
  r[0] = f2bf(fmaf((float)qa.x, s, nzs));
  r[1] = f2bf(fmaf((float)qa.y, s, nzs));
  r[2] = f2bf(fmaf((float)qa.z, s, nzs));
  r[3] = f2bf(fmaf((float)qa.w, s, nzs));
  r[4] = f2bf(fmaf((float)qb.x, s, nzs));
  r[5] = f2bf(fmaf((float)qb.y, s, nzs));
  r[6] = f2bf(fmaf((float)qb.z, s, nzs));
  r[7] = f2bf(fmaf((float)qb.w, s, nzs));
  wb[t] = r;
}

// ---- pass 2: 256x256 8-phase bf16 GEMM ----
// LDS: sA[2 buf][2 half][128*64], sB likewise. 128 KiB total.
// Wave (wr,wc): rows {wr*64..+63} in each A-half, cols {wc*32..+31} in each B-half.
// Phases per K-tile t (buf p=t&1): q0:(A0,B0) q1:(A0,B1) q2:(A1,B1) q3:(A1,B0-in-reg)
// Stages: q0:A1(t+1)->nxt q1:B0(t+1)->nxt q2:A0(t+2)->cur q3:B1(t+2)->cur
// vmcnt(4) at q3 (2 half-tiles in flight); vmcnt(0) at t>=62.

#define BAR() __builtin_amdgcn_s_barrier()
#define LGKM0()                                          \
  do {                                                   \
    asm volatile("s_waitcnt lgkmcnt(0)" ::: "memory");   \
    __builtin_amdgcn_sched_barrier(0);                   \
  } while (0)

__global__ __launch_bounds__(512, 2) void gemm_kernel(const unsigned short* __restrict__ A,
                                                      const unsigned short* __restrict__ B,
                                                      const float* __restrict__ bias,
                                                      float* __restrict__ C) {
  extern __shared__ unsigned short smem[];
  unsigned short* sAb = smem;           // [2][2][8192]
  unsigned short* sBb = smem + 32768;   // [2][2][8192]

  const int bid = blockIdx.x;
  // T1: 1376 blocks, 1376 % 8 == 0 -> simple bijective XCD swizzle.
  const int swz = (bid & 7) * 172 + (bid >> 3);
  const int tm = swz / 43, tn = swz % 43;

  const int tid = threadIdx.x;
  const int w = tid >> 6, l = tid & 63;
  const int wr = w >> 2, wc = w & 3;

  // staging: per global_load_lds, wave covers 8 rows x 128B; 8 waves = 64 rows; 2 issues = 128.
  const int dsto = w * 512 + l * 8;            // LDS elem offset (wave-uniform base + lane*16B)
  const int gs = (l & 7) ^ (l >> 3);           // inverse T2 swizzle on global source slot
  const unsigned short* gA = A + (size_t)(tm * 256 + (tid >> 3)) * K_DIM + gs * 8;
  const unsigned short* gB = B + (size_t)(tn * 256 + (tid >> 3)) * K_DIM + gs * 8;

#define STG_A(tt, h, dst)                                                       \
  do {                                                                          \
    const unsigned short* _s = gA + (size_t)(h) * 128 * K_DIM + (tt) * 64;      \
    gload_lds16(_s, (dst) + dsto);                                              \
    gload_lds16(_s + 64 * K_DIM, (dst) + 4096 + dsto);                          \
  } while (0)
#define STG_B(tt, h, dst)                                                       \
  do {                                                                          \
    const unsigned short* _s = gB + (size_t)(h) * 128 * K_DIM + (tt) * 64;      \
    gload_lds16(_s, (dst) + dsto);                                              \
    gload_lds16(_s + 64 * K_DIM, (dst) + 4096 + dsto);                          \
  } while (0)

  // fragment read coords (16x16x32: lane row=l&15, k-chunk=l>>4, swizzled 16B slots)
  const int fr = l & 15, sb = l >> 4, x7 = l & 7;
  const int abase = (wr * 64 + fr) * 64;
  const int bbase = (wc * 32 + fr) * 64;
  const int k0 = (sb ^ x7) * 8;
  const int k1 = ((sb + 4) ^ x7) * 8;

  bf16x8 av[4][2], bva[2][2], bvb[2][2];
  f32x4 acc[8][4] = {};

#define READ_A(half)                                                     \
  {                                                                      \
    _Pragma("unroll") for (int m = 0; m < 4; ++m) {                      \
      av[m][0] = *(const bf16x8*)((half) + abase + m * 1024 + k0);       \
      av[m][1] = *(const bf16x8*)((half) + abase + m * 1024 + k1);       \
    }                                                                    \
  }
#define READ_B(half, arr)                                                \
  {                                                                      \
    _Pragma("unroll") for (int n = 0; n < 2; ++n) {                      \
      arr[n][0] = *(const bf16x8*)((half) + bbase + n * 1024 + k0);      \
      arr[n][1] = *(const bf16x8*)((half) + bbase + n * 1024 + k1);      \
    }                                                                    \
  }
#define MFMA_Q(mh, nh, arr)                                                        \
  {                                                                                \
    __builtin_amdgcn_s_setprio(1);                                                 \
    _Pragma("unroll") for (int kk = 0; kk < 2; ++kk)                               \
    _Pragma("unroll") for (int m = 0; m < 4; ++m)                                  \
    _Pragma("unroll") for (int nn = 0; nn < 2; ++nn)                               \
      acc[(mh)*4 + m][(nh)*2 + nn] = __builtin_amdgcn_mfma_f32_16x16x32_bf16(      \
          av[m][kk], arr[nn][kk], acc[(mh)*4 + m][(nh)*2 + nn], 0, 0, 0);          \
    __builtin_amdgcn_s_setprio(0);                                                 \
  }

  // ---- prologue: tile0 all 4 halves + A0(1), B1(1) ----
  STG_A(0, 0, sAb);
  STG_A(0, 1, sAb + 8192);
  STG_B(0, 0, sBb);
  STG_B(0, 1, sBb + 8192);
  STG_A(1, 0, sAb + 16384);
  STG_B(1, 1, sBb + 16384 + 8192);
  asm volatile("s_waitcnt vmcnt(4)" ::: "memory");
  BAR();

#pragma unroll 2
  for (int t = 0; t < 64; ++t) {
    const int p = t & 1;
    unsigned short* cA = sAb + p * 16384;
    unsigned short* cB = sBb + p * 16384;
    unsigned short* nA = sAb + (p ^ 1) * 16384;
    unsigned short* nB = sBb + (p ^ 1) * 16384;

    // q0: read A0,B0; stage A1(t+1)
    READ_A(cA);
    READ_B(cB, bva);
    if (t < 63) STG_A(t + 1, 1, nA + 8192);
    BAR();
    LGKM0();
    MFMA_Q(0, 0, bva);
    BAR();

    // q1: read B1; stage B0(t+1)
    READ_B(cB + 8192, bvb);
    if (t < 63) STG_B(t + 1, 0, nB);
    BAR();
    LGKM0();
    MFMA_Q(0, 1, bvb);
    BAR();

    // q2: read A1; stage A0(t+2) (A0 free after q1... last read q1? last read q1 is A0 -> free)
    READ_A(cA + 8192);
    if (t < 62) STG_A(t + 2, 0, cA);
    BAR();
    LGKM0();
    MFMA_Q(1, 1, bvb);
    BAR();

    // q3: B0 frags still live in bva (no re-read); stage B1(t+2)
    if (t < 62) STG_B(t + 2, 1, cB + 8192);
    BAR();
    LGKM0();
    MFMA_Q(1, 0, bva);
    if (t < 62) {
      asm volatile("s_waitcnt vmcnt(4)" ::: "memory");
    } else {
      asm volatile("s_waitcnt vmcnt(0)" ::: "memory");
    }
    BAR();
  }

  // ---- epilogue: C/D layout col=lane&15, row=(lane>>4)*4+reg ----
  const int r0 = tm * 256 + wr * 64 + sb * 4;
  const int c0 = tn * 256 + wc * 32 + fr;
#pragma unroll
  for (int n = 0; n < 4; ++n) {
    const int col = c0 + (n >> 1) * 128 + (n & 1) * 16;
    const float bv = bias[col];
#pragma unroll
    for (int mi = 0; mi < 8; ++mi) {
      const int row = r0 + (mi >> 2) * 128 + (mi & 3) * 16;
#pragma unroll
      for (int jj = 0; jj < 4; ++jj)
        C[(size_t)(row + jj) * N_DIM + col] = acc[mi][n][jj] + bv;
    }
  }
}

extern "C" void kernel_launch(void* const* d_in, const int* in_sizes, int n_in,
                              void* d_out, int out_size, void* d_ws, size_t ws_size,
                              hipStream_t stream) {
  const float* x = (const float*)d_in[0];
  const int* qw = (const int*)d_in[1];
  const float* sc = (const float*)d_in[2];
  const float* zr = (const float*)d_in[3];
  const float* bs = (const float*)d_in[4];
  float* out = (float*)d_out;

  const size_t xb_bytes = (size_t)M_DIM * K_DIM * 2;
  const size_t wb_bytes = (size_t)N_DIM * K_DIM * 2;
  if (ws_size < xb_bytes + wb_bytes) return;

  unsigned short* xb = (unsigned short*)d_ws;
  unsigned short* wb = (unsigned short*)((char*)d_ws + xb_bytes);

  (void)hipFuncSetAttribute((const void*)gemm_kernel,
                            hipFuncAttributeMaxDynamicSharedMemorySize, 131072);

  cvt_x_kernel<<<(M_DIM * K_DIM / 8) / 256, 256, 0, stream>>>((const float4*)x, (u16x8*)xb);
  dequant_kernel<<<(N_DIM * K_DIM / 8) / 256, 256, 0, stream>>>((const int4*)qw, sc, zr,
                                                                (u16x8*)wb);
  gemm_kernel<<<(M_DIM / 256) * (N_DIM / 256), 512, 131072, stream>>>(xb, wb, bs, out);
}

// Round 3
// 733.934 us; speedup vs baseline: 1.4967x; 1.0337x over previous
//
#include <hip/hip_runtime.h>
#include <hip/hip_bf16.h>

// QuantizedLinear: out[m,o] = sum_k x[m,k] * (q[o,k]-z[o,g])*s[o,g] + b[o]
// M=8192, K=4096, N=11008. Pass1: dequant W->bf16, cvt x->bf16 (d_ws).
// Pass2: 256x256 bf16 GEMM, 4 phases/K-tile, ONE barrier per phase,
// compiler-scheduled lgkm waits, counted vmcnt(4) once per K-tile.
// T1 XCD swizzle, T2 LDS swizzle (via inverse-swizzled global source), T5 setprio.

#define K_DIM 4096
#define N_DIM 11008
#define M_DIM 8192
#define NGRP 32

typedef __bf16 bf16x8 __attribute__((ext_vector_type(8)));
typedef float f32x4 __attribute__((ext_vector_type(4)));
typedef unsigned short u16x8 __attribute__((ext_vector_type(8)));

__device__ __forceinline__ unsigned short f2bf(float f) {
  unsigned u = __builtin_bit_cast(unsigned, f);
  return (unsigned short)((u + 0x7FFFu + ((u >> 16) & 1u)) >> 16);  // RNE
}

__device__ __forceinline__ void gload_lds16(const void* g, void* l) {
  __builtin_amdgcn_global_load_lds(
      (const __attribute__((address_space(1))) unsigned int*)(unsigned long long)g,
      (__attribute__((address_space(3))) unsigned int*)(unsigned int)(unsigned long long)l,
      16, 0, 0);
}

// ---- pass 1a: x fp32 -> bf16 ----
__global__ __launch_bounds__(256) void cvt_x_kernel(const float4* __restrict__ x4,
                                                    u16x8* __restrict__ xb) {
  int i = blockIdx.x * 256 + threadIdx.x;
  float4 a = x4[2 * i], b = x4[2 * i + 1];
  u16x8 r;
  r[0] = f2bf(a.x); r[1] = f2bf(a.y); r[2] = f2bf(a.z); r[3] = f2bf(a.w);
  r[4] = f2bf(b.x); r[5] = f2bf(b.y); r[6] = f2bf(b.z); r[7] = f2bf(b.w);
  xb[i] = r;
}

// ---- pass 1b: dequant W -> bf16 ----
__global__ __launch_bounds__(256) void dequant_kernel(const int4* __restrict__ q4,
                                                      const float* __restrict__ scales,
                                                      const float* __restrict__ zeros,
                                                      u16x8* __restrict__ wb) {
  int t = blockIdx.x * 256 + threadIdx.x;
  int o = t >> 9;
  int j8 = t & 511;
  int g = j8 >> 4;
  float s = scales[o * NGRP + g];
  float z = zeros[o * NGRP + g];
  float nzs = -z * s;
  int4 qa = q4[2 * t], qb = q4[2 * t + 1];
  u16x8 r;
  r[0] = f2bf(fmaf((float)qa.x, s, nzs));
  r[1] = f2bf(fmaf((float)qa.y, s, nzs));
  r[2] = f2bf(fmaf((float)qa.z, s, nzs));
  r[3] = f2bf(fmaf((float)qa.w, s, nzs));
  r[4] = f2bf(fmaf((float)qb.x, s, nzs));
  r[5] = f2bf(fmaf((float)qb.y, s, nzs));
  r[6] = f2bf(fmaf((float)qb.z, s, nzs));
  r[7] = f2bf(fmaf((float)qb.w, s, nzs));
  wb[t] = r;
}

// ---- pass 2: 256x256 bf16 GEMM, 4 phases/K-tile, 1 barrier/phase ----
// LDS: sA[2 buf][2 half][128*64], sB likewise. 128 KiB total.
// Phases (tile t, buf p=t&1): q0 MFMA(A0,B0) q1 (A0,B1) q2 (A1,B1) q3 (A1,B0-in-reg)
// Stages: q0 A1(t+1), q1 B0(t+1), q2 A0(t+2), q3 B1(t+2). vmcnt(4) once at q3.
// Safety: phase-q ds_reads retire before phase-q MFMAs issue (compiler lgkm deps),
// so the NEXT pre-MFMA barrier is a sufficient WAR guard for staging; vmcnt(4)
// before q3's barrier covers all of tile t+1's halves chip-wide.

#define BAR() __builtin_amdgcn_s_barrier()
#define SCHED0() __builtin_amdgcn_sched_barrier(0)

__global__ __launch_bounds__(512, 2) void gemm_kernel(const unsigned short* __restrict__ A,
                                                      const unsigned short* __restrict__ B,
                                                      const float* __restrict__ bias,
                                                      float* __restrict__ C) {
  extern __shared__ unsigned short smem[];
  unsigned short* sAb = smem;           // [2][2][8192]
  unsigned short* sBb = smem + 32768;   // [2][2][8192]

  const int bid = blockIdx.x;
  // T1: 1376 blocks, 1376 % 8 == 0 -> simple bijective XCD swizzle.
  const int swz = (bid & 7) * 172 + (bid >> 3);
  const int tm = swz / 43, tn = swz % 43;

  const int tid = threadIdx.x;
  const int w = tid >> 6, l = tid & 63;
  const int wr = w >> 2, wc = w & 3;

  const int dsto = w * 512 + l * 8;            // LDS elem offset (wave base + lane*16B)
  const int gs = (l & 7) ^ (l >> 3);           // inverse T2 swizzle on global source slot
  const unsigned short* gA = A + (size_t)(tm * 256 + (tid >> 3)) * K_DIM + gs * 8;
  const unsigned short* gB = B + (size_t)(tn * 256 + (tid >> 3)) * K_DIM + gs * 8;

#define STG_A(tt, h, dst)                                                       \
  do {                                                                          \
    const unsigned short* _s = gA + (size_t)(h) * 128 * K_DIM + (tt) * 64;      \
    gload_lds16(_s, (dst) + dsto);                                              \
    gload_lds16(_s + 64 * K_DIM, (dst) + 4096 + dsto);                          \
  } while (0)
#define STG_B(tt, h, dst)                                                       \
  do {                                                                          \
    const unsigned short* _s = gB + (size_t)(h) * 128 * K_DIM + (tt) * 64;      \
    gload_lds16(_s, (dst) + dsto);                                              \
    gload_lds16(_s + 64 * K_DIM, (dst) + 4096 + dsto);                          \
  } while (0)

  // fragment read coords (16x16x32: lane row=l&15, k-chunk=l>>4, swizzled 16B slots)
  const int fr = l & 15, sb = l >> 4, x7 = l & 7;
  const int abase = (wr * 64 + fr) * 64;
  const int bbase = (wc * 32 + fr) * 64;
  const int k0 = (sb ^ x7) * 8;
  const int k1 = ((sb + 4) ^ x7) * 8;

  bf16x8 av[4][2], bva[2][2], bvb[2][2];
  f32x4 acc[8][4] = {};

#define READ_A(half)                                                     \
  {                                                                      \
    _Pragma("unroll") for (int m = 0; m < 4; ++m) {                      \
      av[m][0] = *(const bf16x8*)((half) + abase + m * 1024 + k0);       \
      av[m][1] = *(const bf16x8*)((half) + abase + m * 1024 + k1);       \
    }                                                                    \
  }
#define READ_B(half, arr)                                                \
  {                                                                      \
    _Pragma("unroll") for (int n = 0; n < 2; ++n) {                      \
      arr[n][0] = *(const bf16x8*)((half) + bbase + n * 1024 + k0);      \
      arr[n][1] = *(const bf16x8*)((half) + bbase + n * 1024 + k1);      \
    }                                                                    \
  }
#define MFMA_Q(mh, nh, arr)                                                        \
  {                                                                                \
    __builtin_amdgcn_s_setprio(1);                                                 \
    _Pragma("unroll") for (int kk = 0; kk < 2; ++kk)                               \
    _Pragma("unroll") for (int m = 0; m < 4; ++m)                                  \
    _Pragma("unroll") for (int nn = 0; nn < 2; ++nn)                               \
      acc[(mh)*4 + m][(nh)*2 + nn] = __builtin_amdgcn_mfma_f32_16x16x32_bf16(      \
          av[m][kk], arr[nn][kk], acc[(mh)*4 + m][(nh)*2 + nn], 0, 0, 0);          \
    __builtin_amdgcn_s_setprio(0);                                                 \
  }

  // ---- prologue: tile0 all 4 halves + A0(1), B1(1) ----
  STG_A(0, 0, sAb);
  STG_A(0, 1, sAb + 8192);
  STG_B(0, 0, sBb);
  STG_B(0, 1, sBb + 8192);
  STG_A(1, 0, sAb + 16384);
  STG_B(1, 1, sBb + 16384 + 8192);
  asm volatile("s_waitcnt vmcnt(4)" ::: "memory");
  BAR();
  SCHED0();

#pragma unroll 2
  for (int t = 0; t < 64; ++t) {
    const int p = t & 1;
    unsigned short* cA = sAb + p * 16384;
    unsigned short* cB = sBb + p * 16384;
    unsigned short* nA = sAb + (p ^ 1) * 16384;
    unsigned short* nB = sBb + (p ^ 1) * 16384;

    // q0: read A0,B0; stage A1(t+1); MFMA quadrant (0,0)
    READ_A(cA);
    READ_B(cB, bva);
    if (t < 63) STG_A(t + 1, 1, nA + 8192);
    BAR();
    SCHED0();
    MFMA_Q(0, 0, bva);

    // q1: read B1; stage B0(t+1); MFMA (0,1)
    READ_B(cB + 8192, bvb);
    if (t < 63) STG_B(t + 1, 0, nB);
    BAR();
    SCHED0();
    MFMA_Q(0, 1, bvb);

    // q2: read A1; stage A0(t+2); MFMA (1,1)
    READ_A(cA + 8192);
    if (t < 62) STG_A(t + 2, 0, cA);
    BAR();
    SCHED0();
    MFMA_Q(1, 1, bvb);

    // q3: stage B1(t+2); MFMA (1,0) on registers; drain to 4 in flight; barrier
    if (t < 62) STG_B(t + 2, 1, cB + 8192);
    MFMA_Q(1, 0, bva);
    if (t < 62) {
      asm volatile("s_waitcnt vmcnt(4)" ::: "memory");
    } else {
      asm volatile("s_waitcnt vmcnt(0)" ::: "memory");
    }
    BAR();
    SCHED0();
  }

  // ---- epilogue: C/D layout col=lane&15, row=(lane>>4)*4+reg ----
  const int r0 = tm * 256 + wr * 64 + sb * 4;
  const int c0 = tn * 256 + wc * 32 + fr;
#pragma unroll
  for (int n = 0; n < 4; ++n) {
    const int col = c0 + (n >> 1) * 128 + (n & 1) * 16;
    const float bv = bias[col];
#pragma unroll
    for (int mi = 0; mi < 8; ++mi) {
      const int row = r0 + (mi >> 2) * 128 + (mi & 3) * 16;
#pragma unroll
      for (int jj = 0; jj < 4; ++jj)
        C[(size_t)(row + jj) * N_DIM + col] = acc[mi][n][jj] + bv;
    }
  }
}

extern "C" void kernel_launch(void* const* d_in, const int* in_sizes, int n_in,
                              void* d_out, int out_size, void* d_ws, size_t ws_size,
                              hipStream_t stream) {
  const float* x = (const float*)d_in[0];
  const int* qw = (const int*)d_in[1];
  const float* sc = (const float*)d_in[2];
  const float* zr = (const float*)d_in[3];
  const float* bs = (const float*)d_in[4];
  float* out = (float*)d_out;

  const size_t xb_bytes = (size_t)M_DIM * K_DIM * 2;
  const size_t wb_bytes = (size_t)N_DIM * K_DIM * 2;
  if (ws_size < xb_bytes + wb_bytes) return;

  unsigned short* xb = (unsigned short*)d_ws;
  unsigned short* wb = (unsigned short*)((char*)d_ws + xb_bytes);

  (void)hipFuncSetAttribute((const void*)gemm_kernel,
                            hipFuncAttributeMaxDynamicSharedMemorySize, 131072);

  cvt_x_kernel<<<(M_DIM * K_DIM / 8) / 256, 256, 0, stream>>>((const float4*)x, (u16x8*)xb);
  dequant_kernel<<<(N_DIM * K_DIM / 8) / 256, 256, 0, stream>>>((const int4*)qw, sc, zr,
                                                                (u16x8*)wb);
  gemm_kernel<<<(M_DIM / 256) * (N_DIM / 256), 512, 131072, stream>>>(xb, wb, bs, out);
}